// Round 13
// baseline (876.184 us; speedup 1.0000x reference)
//
#include <hip/hip_runtime.h>

// R-GCN layer: out[v] = sum_{e: dst[e]=v} norm[e] * (h[src[e]] @ W[rel[e]])
//
// v13: v12's fused structure with the k_sort RACE fixed (one missing
// __syncthreads). v12 post-mortem: waves 1-3 re-zeroed cnt[][] while wave 0
// was still reading it to build per-wave scatter bases wb[][] -> corrupted
// ranking -> duplicated/stale payload entries -> absmax 7.25. Everything
// else byte-identical to v12:
//   - edges bucketed by 128-dst-node groups (proven hist/scan/scatter2),
//   - k_sort: per-bucket rel-sort (per-wave counters), runs[b][0..32],
//   - k_fuse: per-bucket 16-edge MFMA tiles, hbf gathers (6.4MB L2-resident),
//     packed Wfrag A-fragments, norm in f32, ds_add_f32 into [128][65] LDS
//     tile, single coalesced store. No T table, no k_pre/k_out, no global
//     atomics. ~490MB of T round-trip HBM traffic eliminated.
// payload: x = (dl<<21) | (rel<<16) | src   (src<50000 fits 16 bits)

#define N_NODES 50000
#define N_EDGES 1600000
#define D 64
#define N_REL 32

#define BSHIFT 7                 // 128 nodes per coarse bucket
#define NPB 128
#define NB 391                   // ceil(50000/128)
#define EPB 4096                 // edges per scatter/hist block
#define SC_BLOCKS 391            // ceil(1.6M/4096)
#define SORT_CAP 6144            // bucket capacity (mean 4092, sd 64 -> +32sd)

typedef __attribute__((ext_vector_type(8))) __bf16 bf16x8;
typedef __attribute__((ext_vector_type(4))) __bf16 bf16x4;
typedef __attribute__((ext_vector_type(4))) float f32x4;

// ws layout (bytes):
//   [0x0000, 0x1000)      gcnt[NB] ints
//   [0x1000, 0x2000)      base[NB+1] ints
//   [0x2000, 0x3000)      cursor[NB] ints
//   [0x3000, 0x11000)     runs[NB*33] ints (51.6 KB)
//   [0x100000, 0xD40000)  payload int2[1.6M] (12.8 MB)
//   [0xD40000, 0xD80000)  Wfrag bf16 [32][2][4][64][8]  (256 KB)
//   [0xD80000, 0x13A0000) hbf bf16 [N_NODES][64]  (6.4 MB)

__global__ __launch_bounds__(512) void k_zeroc(int* __restrict__ gcnt) {
    if (threadIdx.x < NB) gcnt[threadIdx.x] = 0;
}

__global__ __launch_bounds__(256) void k_hist2(const int* __restrict__ dst,
                                               int* __restrict__ gcnt) {
    __shared__ int lc[NB];
    for (int b = threadIdx.x; b < NB; b += 256) lc[b] = 0;
    __syncthreads();
    const int e0 = blockIdx.x * EPB;
    #pragma unroll
    for (int j = 0; j < 16; ++j) {
        int e = e0 + j * 256 + threadIdx.x;
        if (e < N_EDGES) atomicAdd(&lc[dst[e] >> BSHIFT], 1);
    }
    __syncthreads();
    for (int b = threadIdx.x; b < NB; b += 256)
        if (lc[b]) atomicAdd(&gcnt[b], lc[b]);
}

// Exclusive scan of gcnt[0..NB) -> base[0..NB], base[NB]=total; cursor=base.
__global__ __launch_bounds__(512) void k_scanc(const int* __restrict__ gcnt,
                                               int* __restrict__ base,
                                               int* __restrict__ cur) {
    const int t = threadIdx.x;
    const int lane = t & 63;
    const int w = t >> 6;
    int v = (t < NB) ? gcnt[t] : 0;
    int x = v;
    #pragma unroll
    for (int d = 1; d < 64; d <<= 1) {
        int n = __shfl_up(x, d, 64);
        if (lane >= d) x += n;
    }
    __shared__ int wt[8];
    if (lane == 63) wt[w] = x;
    __syncthreads();
    if (t == 0) {
        int run = 0;
        #pragma unroll
        for (int i = 0; i < 8; ++i) { int tmp = wt[i]; wt[i] = run; run += tmp; }
    }
    __syncthreads();
    int excl = x - v + wt[w];
    if (t < NB) { base[t] = excl; cur[t] = excl; }
    if (t == NB - 1) base[NB] = excl + v;
}

// Per-block LDS counting sort of 4096 edges into NB coarse buckets, then
// burst-write contiguous per-bucket runs to globally reserved ranges.
__global__ __launch_bounds__(256) void k_scatter2(
        const int* __restrict__ src, const int* __restrict__ dst,
        const int* __restrict__ rel, const float* __restrict__ norm,
        int* __restrict__ cur, int2* __restrict__ pay) {
    __shared__ int cnt[NB];
    __shared__ int bl[NB + 1];
    __shared__ int gb[NB];
    __shared__ unsigned short bid[EPB];
    __shared__ int2 stage[EPB];
    __shared__ int wt[8];

    const int t = threadIdx.x;
    const int lane = t & 63;
    const int w = t >> 6;
    const int e0 = blockIdx.x * EPB;

    for (int b = t; b < NB; b += 256) cnt[b] = 0;
    __syncthreads();

    // pass 1: count
    #pragma unroll
    for (int j = 0; j < 16; ++j) {
        int e = e0 + j * 256 + t;
        if (e < N_EDGES) atomicAdd(&cnt[dst[e] >> BSHIFT], 1);
    }
    __syncthreads();

    // exclusive scan of cnt[0..NB)
    {
        int x0 = (t < NB) ? cnt[t] : 0;
        int x1 = (t + 256 < NB) ? cnt[t + 256] : 0;
        int s0 = x0, s1 = x1;
        #pragma unroll
        for (int d = 1; d < 64; d <<= 1) {
            int n0 = __shfl_up(s0, d, 64);
            int n1 = __shfl_up(s1, d, 64);
            if (lane >= d) { s0 += n0; s1 += n1; }
        }
        if (lane == 63) { wt[w] = s0; wt[4 + w] = s1; }
        __syncthreads();
        if (t == 0) {
            int run = 0;
            #pragma unroll
            for (int i = 0; i < 8; ++i) { int tmp = wt[i]; wt[i] = run; run += tmp; }
        }
        __syncthreads();
        int ex0 = s0 - x0 + wt[w];
        int ex1 = s1 - x1 + wt[4 + w];
        if (t < NB) bl[t] = ex0;
        if (t + 256 < NB) bl[t + 256] = ex1;
        if (t == 0) {
            int tot = (e0 + EPB <= N_EDGES) ? EPB : (N_EDGES > e0 ? N_EDGES - e0 : 0);
            bl[NB] = tot;
        }
    }
    __syncthreads();

    // reserve global ranges (one atomic per non-empty bucket per block)
    for (int b = t; b < NB; b += 256) {
        int c = bl[b + 1] - bl[b];
        gb[b] = c ? atomicAdd(&cur[b], c) : 0;
    }
    for (int b = t; b < NB; b += 256) cnt[b] = 0;
    __syncthreads();

    // pass 2: stage into LDS in bucket-grouped order
    #pragma unroll
    for (int j = 0; j < 16; ++j) {
        int e = e0 + j * 256 + t;
        if (e < N_EDGES) {
            int dv = dst[e];
            int b = dv >> BSHIFT;
            int r = atomicAdd(&cnt[b], 1);
            int pos = bl[b] + r;
            stage[pos] = make_int2(((dv & (NPB - 1)) << 21) | (rel[e] << 16) | src[e],
                                   __float_as_int(norm[e]));
            bid[pos] = (unsigned short)b;
        }
    }
    __syncthreads();

    // pass 3: burst write to global reserved ranges (coalesced runs)
    const int total = bl[NB];
    for (int p = t; p < total; p += 256) {
        int b = bid[p];
        pay[gb[b] + (p - bl[b])] = stage[p];
    }
}

// One block per bucket: stage edges in LDS, counting-sort by REL (per-wave
// counters: contention ~16-way), write back IN PLACE sorted, emit absolute
// per-(bucket,rel) run boundaries runs[b][0..32].
__global__ __launch_bounds__(512) void k_sort(
        const int* __restrict__ base, int2* __restrict__ pay,
        int* __restrict__ runs) {
    __shared__ int2 stage[SORT_CAP];   // 48 KB
    __shared__ int cnt[8][N_REL];
    __shared__ int wb[8][N_REL];
    __shared__ int rbase[N_REL + 1];

    const int t = threadIdx.x;
    const int w = t >> 6;
    const int b = blockIdx.x;
    const int s = base[b];
    const int e = base[b + 1];
    const int n = min(e - s, SORT_CAP);   // clamp: overflow degrades, never faults

    if (t < 256) ((int*)cnt)[t] = 0;
    __syncthreads();

    // stage + per-wave count
    for (int j = t; j < n; j += 512) {
        int2 p = pay[s + j];
        stage[j] = p;
        atomicAdd(&cnt[w][(p.x >> 16) & 31], 1);
    }
    __syncthreads();

    // rel totals + exclusive scan (lanes 0..31 of wave 0) + wave bases
    if (t < N_REL) {
        int tot = 0;
        #pragma unroll
        for (int ww = 0; ww < 8; ++ww) tot += cnt[ww][t];
        int x = tot;
        #pragma unroll
        for (int d = 1; d < 32; d <<= 1) {
            int nn = __shfl_up(x, d, 64);
            if (t >= d) x += nn;
        }
        rbase[t] = x - tot;
        if (t == N_REL - 1) rbase[N_REL] = x;
    }
    __syncthreads();
    if (t < N_REL) {
        int run = rbase[t];
        #pragma unroll
        for (int ww = 0; ww < 8; ++ww) { wb[ww][t] = run; run += cnt[ww][t]; }
        runs[b * 33 + t] = s + rbase[t];
        if (t == 0) runs[b * 33 + N_REL] = s + rbase[N_REL];
    }
    // RACE FIX (v12 bug): wb[][] above reads ALL of cnt[][]; without this
    // barrier, waves 1-3 (which skip the t<N_REL block) zero cnt[][] below
    // while wave 0 is still reading it -> corrupted scatter bases.
    __syncthreads();
    if (t < 256) ((int*)cnt)[t] = 0;
    __syncthreads();

    // rank & scatter back in place, rel-sorted
    for (int j = t; j < n; j += 512) {
        int2 p = stage[j];
        int rv = (p.x >> 16) & 31;
        int pos = wb[w][rv] + atomicAdd(&cnt[w][rv], 1);
        pay[s + pos] = p;
    }
}

// Pack W into per-lane MFMA A-fragment order:
// Wfrag[r][kt][ot][lane][j] = bf16( W[r][kt*32 + (lane>>4)*8 + j][ot*16 + (lane&15)] )
__global__ __launch_bounds__(256) void k_wconv(const float* __restrict__ W,
                                               __bf16* __restrict__ Wfrag) {
    const int r = blockIdx.x;
    const int lane = threadIdx.x & 63;
    const int jj = (threadIdx.x >> 6) * 2;   // 2 elems per thread per frag
    const int q = lane >> 4;
    const int m = lane & 15;
    const float* Wr = W + (size_t)r * D * D;
    #pragma unroll
    for (int kt = 0; kt < 2; ++kt) {
        #pragma unroll
        for (int ot = 0; ot < 4; ++ot) {
            size_t dbase = ((((size_t)r * 2 + kt) * 4 + ot) * 64 + lane) * 8 + jj;
            Wfrag[dbase]     = (__bf16)Wr[(kt * 32 + q * 8 + jj) * D + ot * 16 + m];
            Wfrag[dbase + 1] = (__bf16)Wr[(kt * 32 + q * 8 + jj + 1) * D + ot * 16 + m];
        }
    }
}

// h f32 -> hbf bf16 [N_NODES][64] (6.4 MB, L2/L3-resident gather source).
__global__ __launch_bounds__(512) void k_hconv(const float* __restrict__ h,
                                               __bf16* __restrict__ hbf) {
    int idx = blockIdx.x * 512 + threadIdx.x;   // float4 index, 800000 total
    if (idx < N_NODES * 16) {
        float4 v = ((const float4*)h)[idx];
        bf16x4 o;
        o[0] = (__bf16)v.x; o[1] = (__bf16)v.y; o[2] = (__bf16)v.z; o[3] = (__bf16)v.w;
        ((bf16x4*)hbf)[idx] = o;
    }
}

// Fused per-bucket GEMM+scatter. One block per bucket (128 dst nodes),
// 8 waves. Per rel-run, 16-edge MFMA tiles: gather h rows from hbf as
// B-fragments, A = packed Wfrag, scale by norm (f32), ds_add_f32 into
// [128][65]-padded LDS tile (bank=(dl+off)%32: conflict-free, random dl).
// Epilogue: single plain coalesced store. No T, no global atomics.
__global__ __launch_bounds__(512) void k_fuse(
        const unsigned short* __restrict__ hbf, const __bf16* __restrict__ Wfrag,
        const int* __restrict__ runs, const int2* __restrict__ pay,
        float* __restrict__ out) {
    __shared__ float accL[NPB * 65];   // 33.3 KB
    __shared__ int runsL[N_REL + 1];

    const int t = threadIdx.x;
    const int lane = t & 63;
    const int w = t >> 6;
    const int m = lane & 15;
    const int q = lane >> 4;
    const int b = blockIdx.x;

    for (int j = t; j < NPB * 65; j += 512) accL[j] = 0.f;
    if (t < N_REL + 1) runsL[t] = runs[b * 33 + t];
    __syncthreads();

    const f32x4 vzero = {0.f, 0.f, 0.f, 0.f};
    for (int r = 0; r < N_REL; ++r) {
        const int rs = runsL[r];
        const int re = runsL[r + 1];
        const int ntile = (re - rs + 15) >> 4;
        if (w < ntile) {
            // A fragments for W[r]: 8 coalesced 16B loads (L2-resident)
            bf16x8 wf[2][4];
            #pragma unroll
            for (int kt = 0; kt < 2; ++kt)
                #pragma unroll
                for (int ot = 0; ot < 4; ++ot)
                    wf[kt][ot] = *(const bf16x8*)(Wfrag + ((((size_t)r * 2 + kt) * 4 + ot) * 64 + lane) * 8);

            for (int tl = w; tl < ntile; tl += 8) {
                int ei = rs + tl * 16 + m;
                int2 p = pay[min(ei, re - 1)];
                float nv = (ei < re) ? __int_as_float(p.y) : 0.f;
                int sv = p.x & 0xFFFF;
                int dl = ((unsigned)p.x) >> 21;
                const unsigned short* hrow = hbf + ((size_t)sv << 6);
                bf16x8 a0 = *(const bf16x8*)(hrow + q * 8);
                bf16x8 a1 = *(const bf16x8*)(hrow + 32 + q * 8);
                f32x4 acc[4];
                #pragma unroll
                for (int ot = 0; ot < 4; ++ot) acc[ot] = vzero;
                #pragma unroll
                for (int ot = 0; ot < 4; ++ot) {
                    acc[ot] = __builtin_amdgcn_mfma_f32_16x16x32_bf16(wf[0][ot], a0, acc[ot], 0, 0, 0);
                    acc[ot] = __builtin_amdgcn_mfma_f32_16x16x32_bf16(wf[1][ot], a1, acc[ot], 0, 0, 0);
                }
                // C: col = m (edge), row = ot*16 + q*4 + reg (out dim)
                float* arow = accL + dl * 65;
                #pragma unroll
                for (int ot = 0; ot < 4; ++ot)
                    #pragma unroll
                    for (int reg = 0; reg < 4; ++reg)
                        atomicAdd(arow + ot * 16 + q * 4 + reg, acc[ot][reg] * nv);
            }
        }
    }
    __syncthreads();

    const int node0 = b * NPB;
    for (int idx = t; idx < NPB * D; idx += 512) {
        int row = idx >> 6;
        int node = node0 + row;
        if (node < N_NODES) out[(size_t)node * D + (idx & 63)] = accL[row * 65 + (idx & 63)];
    }
}

extern "C" void kernel_launch(void* const* d_in, const int* in_sizes, int n_in,
                              void* d_out, int out_size, void* d_ws, size_t ws_size,
                              hipStream_t stream) {
    const float* h    = (const float*)d_in[0];
    const float* W    = (const float*)d_in[1];
    const int*   src  = (const int*)d_in[2];
    const int*   dst  = (const int*)d_in[3];
    const int*   rel  = (const int*)d_in[4];
    const float* norm = (const float*)d_in[5];
    float* out = (float*)d_out;

    char* ws = (char*)d_ws;
    int*    gcnt  = (int*)(ws);
    int*    base  = (int*)(ws + 0x1000);
    int*    cur   = (int*)(ws + 0x2000);
    int*    runs  = (int*)(ws + 0x3000);
    int2*   pay   = (int2*)(ws + 0x100000);
    __bf16* Wfrag = (__bf16*)(ws + 0xD40000);
    __bf16* hbf   = (__bf16*)(ws + 0xD80000);

    k_zeroc<<<1, 512, 0, stream>>>(gcnt);
    k_wconv<<<N_REL, 256, 0, stream>>>(W, Wfrag);
    k_hconv<<<1563, 512, 0, stream>>>(h, hbf);
    k_hist2<<<SC_BLOCKS, 256, 0, stream>>>(dst, gcnt);
    k_scanc<<<1, 512, 0, stream>>>(gcnt, base, cur);
    k_scatter2<<<SC_BLOCKS, 256, 0, stream>>>(src, dst, rel, norm, cur, pay);
    k_sort<<<NB, 512, 0, stream>>>(base, pay, runs);
    k_fuse<<<NB, 512, 0, stream>>>((const unsigned short*)hbf, Wfrag, runs, pay, out);
}

// Round 14
// 229.054 us; speedup vs baseline: 3.8252x; 3.8252x over previous
//
#include <hip/hip_runtime.h>

// R-GCN layer: out[v] = sum_{e: dst[e]=v} norm[e] * (h[src[e]] @ W[rel[e]])
//
// v14: fused structure with the LDS-atomic accumulator replaced by a CHAINED
// MFMA scatter. v13 post-mortem (matches v4): ~102M ds_add_f32 lane-ops run
// at ~0.2 lane-ops/cy/CU on gfx950 -> 745us with all pipes idle. Bulk LDS
// atomics are a no-go. Instead, the dst-scatter IS a matmul:
//   MFMA1 (16x16x32 bf16): D1[edge][dim] = h_gather x Wfrag  (C: lane(m,q)
//     holds edges q*4+reg, dim m)
//   MFMA2 (16x16x16 f16):  acc2[dl][dim] += S x D1, where S[dl][edge] =
//     norm_e * (dl_e==dl) is a one-hot scatter matrix built from 4 shuffles.
//   KEY: MFMA1's C-register layout IS MFMA2's B-operand layout (B[k=q*4+j]
//   [col=m]) -- no cross-lane data movement between the two MFMAs.
// Each wave owns a 16-dst sub-bucket; acc2 = 16 VGPRs for the whole bucket;
// epilogue = plain coalesced stores. No LDS in the hot loop, no atomics.
// k_sort key: (dl>>4)*32 + rel (256-way), runs[b][0..256].
// payload: x = (dl<<21) | (rel<<16) | src   (src<50000 fits 16 bits)

#define N_NODES 50000
#define N_EDGES 1600000
#define D 64
#define N_REL 32

#define BSHIFT 7                 // 128 nodes per coarse bucket
#define NPB 128
#define NB 391                   // ceil(50000/128)
#define EPB 4096                 // edges per scatter/hist block
#define SC_BLOCKS 391            // ceil(1.6M/4096)
#define SORT_CAP 6144            // bucket capacity (mean 4092, sd 64 -> +32sd)
#define NKEY 256                 // 8 sub-buckets x 32 rels

typedef __attribute__((ext_vector_type(8))) __bf16 bf16x8;
typedef __attribute__((ext_vector_type(4))) __bf16 bf16x4;
typedef __attribute__((ext_vector_type(4))) float f32x4;
typedef __attribute__((ext_vector_type(4))) _Float16 f16x4;

static __device__ inline unsigned short f16_bits(_Float16 v) {
    union { _Float16 f; unsigned short u; } cv; cv.f = v; return cv.u;
}
static __device__ inline _Float16 bits_f16(unsigned short u) {
    union { _Float16 f; unsigned short u; } cv; cv.u = u; return cv.f;
}

// ws layout (bytes):
//   [0x0000, 0x1000)      gcnt[NB] ints
//   [0x1000, 0x2000)      base[NB+1] ints
//   [0x2000, 0x3000)      cursor[NB] ints
//   [0x3000, 0x66000)     runs[NB*257] ints (402 KB)
//   [0x100000, 0xD40000)  payload int2[1.6M] (12.8 MB)
//   [0xD40000, 0xD80000)  Wfrag bf16 [32][2][4][64][8]  (256 KB)
//   [0xD80000, 0x13A0000) hbf bf16 [N_NODES][64]  (6.4 MB)

__global__ __launch_bounds__(512) void k_zeroc(int* __restrict__ gcnt) {
    if (threadIdx.x < NB) gcnt[threadIdx.x] = 0;
}

__global__ __launch_bounds__(256) void k_hist2(const int* __restrict__ dst,
                                               int* __restrict__ gcnt) {
    __shared__ int lc[NB];
    for (int b = threadIdx.x; b < NB; b += 256) lc[b] = 0;
    __syncthreads();
    const int e0 = blockIdx.x * EPB;
    #pragma unroll
    for (int j = 0; j < 16; ++j) {
        int e = e0 + j * 256 + threadIdx.x;
        if (e < N_EDGES) atomicAdd(&lc[dst[e] >> BSHIFT], 1);
    }
    __syncthreads();
    for (int b = threadIdx.x; b < NB; b += 256)
        if (lc[b]) atomicAdd(&gcnt[b], lc[b]);
}

// Exclusive scan of gcnt[0..NB) -> base[0..NB], base[NB]=total; cursor=base.
__global__ __launch_bounds__(512) void k_scanc(const int* __restrict__ gcnt,
                                               int* __restrict__ base,
                                               int* __restrict__ cur) {
    const int t = threadIdx.x;
    const int lane = t & 63;
    const int w = t >> 6;
    int v = (t < NB) ? gcnt[t] : 0;
    int x = v;
    #pragma unroll
    for (int d = 1; d < 64; d <<= 1) {
        int n = __shfl_up(x, d, 64);
        if (lane >= d) x += n;
    }
    __shared__ int wt[8];
    if (lane == 63) wt[w] = x;
    __syncthreads();
    if (t == 0) {
        int run = 0;
        #pragma unroll
        for (int i = 0; i < 8; ++i) { int tmp = wt[i]; wt[i] = run; run += tmp; }
    }
    __syncthreads();
    int excl = x - v + wt[w];
    if (t < NB) { base[t] = excl; cur[t] = excl; }
    if (t == NB - 1) base[NB] = excl + v;
}

// Per-block LDS counting sort of 4096 edges into NB coarse buckets, then
// burst-write contiguous per-bucket runs to globally reserved ranges.
__global__ __launch_bounds__(256) void k_scatter2(
        const int* __restrict__ src, const int* __restrict__ dst,
        const int* __restrict__ rel, const float* __restrict__ norm,
        int* __restrict__ cur, int2* __restrict__ pay) {
    __shared__ int cnt[NB];
    __shared__ int bl[NB + 1];
    __shared__ int gb[NB];
    __shared__ unsigned short bid[EPB];
    __shared__ int2 stage[EPB];
    __shared__ int wt[8];

    const int t = threadIdx.x;
    const int lane = t & 63;
    const int w = t >> 6;
    const int e0 = blockIdx.x * EPB;

    for (int b = t; b < NB; b += 256) cnt[b] = 0;
    __syncthreads();

    // pass 1: count
    #pragma unroll
    for (int j = 0; j < 16; ++j) {
        int e = e0 + j * 256 + t;
        if (e < N_EDGES) atomicAdd(&cnt[dst[e] >> BSHIFT], 1);
    }
    __syncthreads();

    // exclusive scan of cnt[0..NB)
    {
        int x0 = (t < NB) ? cnt[t] : 0;
        int x1 = (t + 256 < NB) ? cnt[t + 256] : 0;
        int s0 = x0, s1 = x1;
        #pragma unroll
        for (int d = 1; d < 64; d <<= 1) {
            int n0 = __shfl_up(s0, d, 64);
            int n1 = __shfl_up(s1, d, 64);
            if (lane >= d) { s0 += n0; s1 += n1; }
        }
        if (lane == 63) { wt[w] = s0; wt[4 + w] = s1; }
        __syncthreads();
        if (t == 0) {
            int run = 0;
            #pragma unroll
            for (int i = 0; i < 8; ++i) { int tmp = wt[i]; wt[i] = run; run += tmp; }
        }
        __syncthreads();
        int ex0 = s0 - x0 + wt[w];
        int ex1 = s1 - x1 + wt[4 + w];
        if (t < NB) bl[t] = ex0;
        if (t + 256 < NB) bl[t + 256] = ex1;
        if (t == 0) {
            int tot = (e0 + EPB <= N_EDGES) ? EPB : (N_EDGES > e0 ? N_EDGES - e0 : 0);
            bl[NB] = tot;
        }
    }
    __syncthreads();

    // reserve global ranges (one atomic per non-empty bucket per block)
    for (int b = t; b < NB; b += 256) {
        int c = bl[b + 1] - bl[b];
        gb[b] = c ? atomicAdd(&cur[b], c) : 0;
    }
    for (int b = t; b < NB; b += 256) cnt[b] = 0;
    __syncthreads();

    // pass 2: stage into LDS in bucket-grouped order
    #pragma unroll
    for (int j = 0; j < 16; ++j) {
        int e = e0 + j * 256 + t;
        if (e < N_EDGES) {
            int dv = dst[e];
            int b = dv >> BSHIFT;
            int r = atomicAdd(&cnt[b], 1);
            int pos = bl[b] + r;
            stage[pos] = make_int2(((dv & (NPB - 1)) << 21) | (rel[e] << 16) | src[e],
                                   __float_as_int(norm[e]));
            bid[pos] = (unsigned short)b;
        }
    }
    __syncthreads();

    // pass 3: burst write to global reserved ranges (coalesced runs)
    const int total = bl[NB];
    for (int p = t; p < total; p += 256) {
        int b = bid[p];
        pay[gb[b] + (p - bl[b])] = stage[p];
    }
}

// One block per bucket: stage edges in LDS, counting-sort by 8-bit key
// (sub-bucket dl>>4, rel) with per-wave counters, write back IN PLACE,
// emit absolute run boundaries runs[b][0..256].
__global__ __launch_bounds__(512) void k_sort(
        const int* __restrict__ base, int2* __restrict__ pay,
        int* __restrict__ runs) {
    __shared__ int2 stage[SORT_CAP];   // 48 KB
    __shared__ int cnt[8][NKEY];       // 8 KB
    __shared__ int wb[8][NKEY];        // 8 KB
    __shared__ int kbase[NKEY];
    __shared__ int wsum[8];

    const int t = threadIdx.x;
    const int lane = t & 63;
    const int w = t >> 6;
    const int b = blockIdx.x;
    const int s = base[b];
    const int e = base[b + 1];
    const int n = min(e - s, SORT_CAP);   // clamp: overflow degrades, never faults

    for (int j = t; j < 8 * NKEY; j += 512) ((int*)cnt)[j] = 0;
    __syncthreads();

    // stage + per-wave count
    for (int j = t; j < n; j += 512) {
        int2 p = pay[s + j];
        stage[j] = p;
        int key = (((p.x >> 25) & 7) << 5) | ((p.x >> 16) & 31);
        atomicAdd(&cnt[w][key], 1);
    }
    __syncthreads();

    // key totals + block-wide exclusive scan over 256 keys
    int tot = 0;
    if (t < NKEY) {
        #pragma unroll
        for (int ww = 0; ww < 8; ++ww) tot += cnt[ww][t];
    }
    int x = tot;
    #pragma unroll
    for (int d = 1; d < 64; d <<= 1) {
        int nn = __shfl_up(x, d, 64);
        if (lane >= d) x += nn;
    }
    if (lane == 63) wsum[w] = x;
    __syncthreads();
    if (t == 0) {
        int run = 0;
        #pragma unroll
        for (int i = 0; i < 8; ++i) { int tmp = wsum[i]; wsum[i] = run; run += tmp; }
    }
    __syncthreads();
    int excl = x - tot + wsum[w];
    if (t < NKEY) kbase[t] = excl;
    __syncthreads();

    // per-wave scatter bases + emit runs
    if (t < NKEY) {
        int run = kbase[t];
        #pragma unroll
        for (int ww = 0; ww < 8; ++ww) { wb[ww][t] = run; run += cnt[ww][t]; }
        runs[b * (NKEY + 1) + t] = s + kbase[t];
    }
    if (t == 0) runs[b * (NKEY + 1) + NKEY] = s + n;
    // barrier BEFORE re-zeroing cnt (v12 race lesson: wb reads all of cnt)
    __syncthreads();
    for (int j = t; j < 8 * NKEY; j += 512) ((int*)cnt)[j] = 0;
    __syncthreads();

    // rank & scatter back in place, key-sorted
    for (int j = t; j < n; j += 512) {
        int2 p = stage[j];
        int key = (((p.x >> 25) & 7) << 5) | ((p.x >> 16) & 31);
        int pos = wb[w][key] + atomicAdd(&cnt[w][key], 1);
        pay[s + pos] = p;
    }
}

// Pack W into per-lane MFMA fragment order (works as A or B slot — the
// 16x16x32 A/B per-lane layouts are symmetric):
// Wfrag[r][kt][ot][lane][j] = bf16( W[r][kt*32 + (lane>>4)*8 + j][ot*16 + (lane&15)] )
__global__ __launch_bounds__(256) void k_wconv(const float* __restrict__ W,
                                               __bf16* __restrict__ Wfrag) {
    const int r = blockIdx.x;
    const int lane = threadIdx.x & 63;
    const int jj = (threadIdx.x >> 6) * 2;   // 2 elems per thread per frag
    const int q = lane >> 4;
    const int m = lane & 15;
    const float* Wr = W + (size_t)r * D * D;
    #pragma unroll
    for (int kt = 0; kt < 2; ++kt) {
        #pragma unroll
        for (int ot = 0; ot < 4; ++ot) {
            size_t dbase = ((((size_t)r * 2 + kt) * 4 + ot) * 64 + lane) * 8 + jj;
            Wfrag[dbase]     = (__bf16)Wr[(kt * 32 + q * 8 + jj) * D + ot * 16 + m];
            Wfrag[dbase + 1] = (__bf16)Wr[(kt * 32 + q * 8 + jj + 1) * D + ot * 16 + m];
        }
    }
}

// h f32 -> hbf bf16 [N_NODES][64] (6.4 MB, L2/L3-resident gather source).
__global__ __launch_bounds__(512) void k_hconv(const float* __restrict__ h,
                                               __bf16* __restrict__ hbf) {
    int idx = blockIdx.x * 512 + threadIdx.x;   // float4 index, 800000 total
    if (idx < N_NODES * 16) {
        float4 v = ((const float4*)h)[idx];
        bf16x4 o;
        o[0] = (__bf16)v.x; o[1] = (__bf16)v.y; o[2] = (__bf16)v.z; o[3] = (__bf16)v.w;
        ((bf16x4*)hbf)[idx] = o;
    }
}

// Fused per-bucket GEMM with chained-MFMA dst-scatter. One block per bucket,
// 8 waves; wave w owns sub-bucket w (16 dst nodes), processing its 32
// rel-runs. Per 16-edge tile:
//   MFMA1: D1[edge][dim] = h_gather(A) x Wfrag(B)   [2x k=32, 4 ot blocks]
//   A2 one-hot: S[dl][edge] = norm_e*(dl_e==dl)      [4 shuffles, in-register]
//   MFMA2: acc2[dl][dim] += S x fp16(D1)             [16x16x16 f16, 4 ot]
// acc2 stays in 16 VGPRs for the whole bucket; epilogue = plain stores.
__global__ __launch_bounds__(512) void k_fuse(
        const unsigned short* __restrict__ hbf, const __bf16* __restrict__ Wfrag,
        const int* __restrict__ runs, const int2* __restrict__ pay,
        float* __restrict__ out) {
    __shared__ int runsL[NKEY + 1];

    const int t = threadIdx.x;
    const int lane = t & 63;
    const int w = t >> 6;
    const int m = lane & 15;
    const int q = lane >> 4;
    const int b = blockIdx.x;

    for (int j = t; j < NKEY + 1; j += 512) runsL[j] = runs[b * (NKEY + 1) + j];
    __syncthreads();

    const f32x4 vzero = {0.f, 0.f, 0.f, 0.f};
    f32x4 acc2[4];
    #pragma unroll
    for (int ot = 0; ot < 4; ++ot) acc2[ot] = vzero;

    const int kb = w * 32;
    for (int r = 0; r < N_REL; ++r) {
        const int rs = runsL[kb + r];
        const int re = runsL[kb + r + 1];
        if (re <= rs) continue;

        // W fragments for rel r: 8 coalesced 16B loads (L2-resident)
        bf16x8 wf[2][4];
        #pragma unroll
        for (int kt = 0; kt < 2; ++kt)
            #pragma unroll
            for (int ot = 0; ot < 4; ++ot)
                wf[kt][ot] = *(const bf16x8*)(Wfrag + ((((size_t)r * 2 + kt) * 4 + ot) * 64 + lane) * 8);

        const int ntile = (re - rs + 15) >> 4;
        for (int tl = 0; tl < ntile; ++tl) {
            int ei = rs + tl * 16 + m;
            int2 p = pay[min(ei, re - 1)];
            float nvf = (ei < re) ? __int_as_float(p.y) : 0.f;
            int meta = (((p.x >> 21) & 15) << 16) | f16_bits((_Float16)nvf);

            const unsigned short* hrow = hbf + ((size_t)(p.x & 0xFFFF) << 6);
            bf16x8 a0 = *(const bf16x8*)(hrow + q * 8);
            bf16x8 a1 = *(const bf16x8*)(hrow + 32 + q * 8);

            // MFMA1: D1[edge][dim] (lane(m,q): edges q*4+reg, dim m)
            f32x4 c1[4];
            #pragma unroll
            for (int ot = 0; ot < 4; ++ot) {
                c1[ot] = __builtin_amdgcn_mfma_f32_16x16x32_bf16(a0, wf[0][ot], vzero, 0, 0, 0);
                c1[ot] = __builtin_amdgcn_mfma_f32_16x16x32_bf16(a1, wf[1][ot], c1[ot], 0, 0, 0);
            }

            // A2 one-hot: lane(m,q) holds S[row=m][k=q*4+j]
            f16x4 a2;
            #pragma unroll
            for (int j = 0; j < 4; ++j) {
                int sm = __shfl(meta, q * 4 + j, 64);
                _Float16 nv = bits_f16((unsigned short)(sm & 0xFFFF));
                a2[j] = ((sm >> 16) == m) ? nv : (_Float16)0.f;
            }

            // MFMA2: acc2[dl][dim] += S x fp16(D1); B2 = c1 (layout match)
            #pragma unroll
            for (int ot = 0; ot < 4; ++ot) {
                f16x4 b2;
                b2[0] = (_Float16)c1[ot][0];
                b2[1] = (_Float16)c1[ot][1];
                b2[2] = (_Float16)c1[ot][2];
                b2[3] = (_Float16)c1[ot][3];
                acc2[ot] = __builtin_amdgcn_mfma_f32_16x16x16f16(a2, b2, acc2[ot], 0, 0, 0);
            }
        }
    }

    // epilogue: lane(m,q) holds acc2[ot][reg] = out[sub*16 + q*4+reg][ot*16+m]
    const int node_base = b * NPB + w * 16;
    #pragma unroll
    for (int reg = 0; reg < 4; ++reg) {
        int node = node_base + q * 4 + reg;
        if (node < N_NODES) {
            float* orow = out + (size_t)node * D + m;
            #pragma unroll
            for (int ot = 0; ot < 4; ++ot)
                orow[ot * 16] = acc2[ot][reg];
        }
    }
}

extern "C" void kernel_launch(void* const* d_in, const int* in_sizes, int n_in,
                              void* d_out, int out_size, void* d_ws, size_t ws_size,
                              hipStream_t stream) {
    const float* h    = (const float*)d_in[0];
    const float* W    = (const float*)d_in[1];
    const int*   src  = (const int*)d_in[2];
    const int*   dst  = (const int*)d_in[3];
    const int*   rel  = (const int*)d_in[4];
    const float* norm = (const float*)d_in[5];
    float* out = (float*)d_out;

    char* ws = (char*)d_ws;
    int*    gcnt  = (int*)(ws);
    int*    base  = (int*)(ws + 0x1000);
    int*    cur   = (int*)(ws + 0x2000);
    int*    runs  = (int*)(ws + 0x3000);
    int2*   pay   = (int2*)(ws + 0x100000);
    __bf16* Wfrag = (__bf16*)(ws + 0xD40000);
    __bf16* hbf   = (__bf16*)(ws + 0xD80000);

    k_zeroc<<<1, 512, 0, stream>>>(gcnt);
    k_wconv<<<N_REL, 256, 0, stream>>>(W, Wfrag);
    k_hconv<<<1563, 512, 0, stream>>>(h, hbf);
    k_hist2<<<SC_BLOCKS, 256, 0, stream>>>(dst, gcnt);
    k_scanc<<<1, 512, 0, stream>>>(gcnt, base, cur);
    k_scatter2<<<SC_BLOCKS, 256, 0, stream>>>(src, dst, rel, norm, cur, pay);
    k_sort<<<NB, 512, 0, stream>>>(base, pay, runs);
    k_fuse<<<NB, 512, 0, stream>>>((const unsigned short*)hbf, Wfrag, runs, pay, out);
}